// Round 5
// baseline (491.460 us; speedup 1.0000x reference)
//
#include <hip/hip_runtime.h>
#include <hip/hip_bf16.h>

#define NHEAD 8
#define CDIM 12
#define DMODEL 96
#define BSH 6           // 64 nodes per bucket
#define BCAP 1536       // record capacity per bucket (mean ~1090, +14 sigma)

// ---------------- fused GEMM + attention coefficients ----------------
// H[N,96] = X[N,K] @ W[K,96];  a_s[n,h] = dot(h[n,h,:], att_s[h,:]);  same a_d.
// block: 192 threads = (c4 = t/8 in 0..23, y = t%8 in 0..7); 32 nodes/block.
// Each thread: 4 nodes x 4 cols register tile. W staged in 32-row chunks with
// register prefetch (global latency hides under FMA loop).
template<int K>
__global__ __launch_bounds__(192) void gemm_att_fused(
    const float* __restrict__ X, const float* __restrict__ W,
    const float* __restrict__ att_s, const float* __restrict__ att_d,
    float* __restrict__ H, float* __restrict__ a_s, float* __restrict__ a_d,
    int N)
{
    constexpr int KQ = K / 4;
    __shared__ float xs[K][40];        // X^T tile, XOR-swizzled cols
    __shared__ float wsh[32 * 96];     // W chunk (32 rows, 12 KB)
    __shared__ float red[32][16];      // [node][head*2 + (s|d)]
    const int t  = threadIdx.x;
    const int c4 = t / 8;              // 0..23
    const int y  = t % 8;              // 0..7
    const int n0 = blockIdx.x * 32;

    for (int e = t; e < 512; e += 192) ((float*)red)[e] = 0.f;

    // stage X tile, transposed, XOR-swizzled (coalesced 512B global reads)
    for (int e = t; e < 32 * KQ; e += 192) {
        int n = e / KQ, kq = e % KQ;
        int gn = n0 + n;
        float4 v = make_float4(0.f, 0.f, 0.f, 0.f);
        if (gn < N) v = ((const float4*)(X + (size_t)gn * K))[kq];
        int ncol = n ^ ((kq & 7) << 2);
        xs[4 * kq + 0][ncol] = v.x;
        xs[4 * kq + 1][ncol] = v.y;
        xs[4 * kq + 2][ncol] = v.z;
        xs[4 * kq + 3][ncol] = v.w;
    }

    // prefetch W chunk 0 into registers (32 rows * 24 float4 = 768 = 4*192)
    float4 pref[4];
#pragma unroll
    for (int p = 0; p < 4; ++p)
        pref[p] = ((const float4*)W)[t + p * 192];

    float4 acc[4];
#pragma unroll
    for (int i = 0; i < 4; ++i) acc[i] = make_float4(0.f, 0.f, 0.f, 0.f);

    for (int k0 = 0; k0 < K; k0 += 32) {
        __syncthreads();               // previous chunk fully consumed
#pragma unroll
        for (int p = 0; p < 4; ++p) ((float4*)wsh)[t + p * 192] = pref[p];
        __syncthreads();
        if (k0 + 32 < K) {             // prefetch next chunk (hides under FMAs)
#pragma unroll
            for (int p = 0; p < 4; ++p)
                pref[p] = ((const float4*)(W + (size_t)(k0 + 32) * 96))[t + p * 192];
        }
#pragma unroll 4
        for (int kk = 0; kk < 32; ++kk) {
            const int k = k0 + kk;
            const float4 wv = *(const float4*)&wsh[kk * 96 + c4 * 4];
            const int q = (k >> 2) & 7;
            const float4 xv = *(const float4*)&xs[k][4 * (y ^ q)];
            acc[0].x = fmaf(xv.x, wv.x, acc[0].x);
            acc[0].y = fmaf(xv.x, wv.y, acc[0].y);
            acc[0].z = fmaf(xv.x, wv.z, acc[0].z);
            acc[0].w = fmaf(xv.x, wv.w, acc[0].w);
            acc[1].x = fmaf(xv.y, wv.x, acc[1].x);
            acc[1].y = fmaf(xv.y, wv.y, acc[1].y);
            acc[1].z = fmaf(xv.y, wv.z, acc[1].z);
            acc[1].w = fmaf(xv.y, wv.w, acc[1].w);
            acc[2].x = fmaf(xv.z, wv.x, acc[2].x);
            acc[2].y = fmaf(xv.z, wv.y, acc[2].y);
            acc[2].z = fmaf(xv.z, wv.z, acc[2].z);
            acc[2].w = fmaf(xv.z, wv.w, acc[2].w);
            acc[3].x = fmaf(xv.w, wv.x, acc[3].x);
            acc[3].y = fmaf(xv.w, wv.y, acc[3].y);
            acc[3].z = fmaf(xv.w, wv.z, acc[3].z);
            acc[3].w = fmaf(xv.w, wv.w, acc[3].w);
        }
    }

    // ---- fused attention-coefficient partials ----
    const int h = c4 / 3;
    const float4 asv = ((const float4*)att_s)[c4];
    const float4 adv = ((const float4*)att_d)[c4];
#pragma unroll
    for (int i = 0; i < 4; ++i) {
        const int m = 4 * y + i;
        float ps = acc[i].x * asv.x + acc[i].y * asv.y
                 + acc[i].z * asv.z + acc[i].w * asv.w;
        float pd = acc[i].x * adv.x + acc[i].y * adv.y
                 + acc[i].z * adv.z + acc[i].w * adv.w;
        atomicAdd(&red[m][h * 2 + 0], ps);
        atomicAdd(&red[m][h * 2 + 1], pd);
    }

    // ---- H store ----
#pragma unroll
    for (int i = 0; i < 4; ++i) {
        const int gn = n0 + 4 * y + i;
        if (gn < N) ((float4*)(H + (size_t)gn * 96))[c4] = acc[i];
    }

    __syncthreads();
    for (int e = t; e < 256; e += 192) {
        const int m = e >> 3, hh = e & 7;
        const int gn = n0 + m;
        if (gn < N) {
            a_s[gn * NHEAD + hh] = red[m][hh * 2 + 0];
            a_d[gn * NHEAD + hh] = red[m][hh * 2 + 1];
        }
    }
}

// ---------------- CSR build: bucketed two-phase scatter ----------------
// Phase A: append (d,s) records to per-bucket region (streaming writes) +
// degree histogram. Phase B: scatter within bucket; col[] window per bucket
// is ~4KB -> L2-resident random writes.
__global__ void bucketA_kernel(const int* __restrict__ srci, const int* __restrict__ dsti,
                               int* __restrict__ bcnt, int* __restrict__ deg,
                               int2* __restrict__ brec, int E0, int Etot)
{
    int e = blockIdx.x * blockDim.x + threadIdx.x;
    if (e >= Etot) return;
    int s, d;
    if (e < E0) { s = srci[e]; d = dsti[e]; }
    else        { s = d = e - E0; }
    atomicAdd(&deg[d], 1);
    int b = d >> BSH;
    int p = atomicAdd(&bcnt[b], 1);
    if (p < BCAP) brec[(size_t)b * BCAP + p] = make_int2(d, s);
}

__global__ __launch_bounds__(256) void bucketB_kernel(
    const int* __restrict__ bcnt, const int2* __restrict__ brec,
    int* __restrict__ cnt, int* __restrict__ col)
{
    int b = blockIdx.x;
    int n = bcnt[b];
    if (n > BCAP) n = BCAP;
    const int2* r = brec + (size_t)b * BCAP;
    for (int i = threadIdx.x; i < n; i += 256) {
        int2 v = r[i];
        int pos = atomicAdd(&cnt[v.x], 1);
        col[pos] = v.y;
    }
}

__global__ __launch_bounds__(1024) void scan_block_kernel(
    const int* __restrict__ deg, int* __restrict__ rowptr,
    int* __restrict__ bsum, int N)
{
    __shared__ int sh[1024];
    int t = threadIdx.x, g = blockIdx.x * 1024 + t;
    int v = (g < N) ? deg[g] : 0;
    sh[t] = v;
    __syncthreads();
    for (int off = 1; off < 1024; off <<= 1) {
        int add = (t >= off) ? sh[t - off] : 0;
        __syncthreads();
        sh[t] += add;
        __syncthreads();
    }
    if (g < N) rowptr[g] = sh[t] - v;   // exclusive scan
    if (t == 1023) bsum[blockIdx.x] = sh[t];
}

__global__ void scan_bsum_kernel(int* bsum, int nb)
{
    if (threadIdx.x == 0) {
        int acc = 0;
        for (int i = 0; i < nb; ++i) { int v = bsum[i]; bsum[i] = acc; acc += v; }
    }
}

__global__ void scan_add_kernel(int* __restrict__ rowptr, const int* __restrict__ bsum,
                                int N, int Etot)
{
    int g = blockIdx.x * blockDim.x + threadIdx.x;
    if (g < N) rowptr[g] += bsum[g >> 10];
    if (g == 0) rowptr[N] = Etot;
}

// ---------------- edge pass (CSR): gather + fused softmax-denominator ----------------
__global__ __launch_bounds__(384) void edge2_vec_kernel(
    const int* __restrict__ rowptr, const int* __restrict__ col,
    const float* __restrict__ H, const float* __restrict__ a_s,
    const float* __restrict__ a_d, const float* __restrict__ bias,
    float* __restrict__ out, int N)
{
    const int grp  = threadIdx.x / 24;      // 16 nodes/block
    const int lane = threadIdx.x % 24;      // float4 chunk
    const int d = blockIdx.x * 16 + grp;
    if (d >= N) return;
    const int hh = lane / 3;                // head of this chunk
    const float ad  = a_d[d * NHEAD + hh];
    const float4* __restrict__ H4 = (const float4*)H;

    int j0 = rowptr[d], j1 = rowptr[d + 1];
    float4 acc = make_float4(0.f, 0.f, 0.f, 0.f);
    float den = 1e-16f;
    int j = j0;
    for (; j + 3 < j1; j += 4) {
        int s0 = col[j], s1 = col[j+1], s2 = col[j+2], s3 = col[j+3];
        float v0 = a_s[s0 * NHEAD + hh] + ad;
        float v1 = a_s[s1 * NHEAD + hh] + ad;
        float v2 = a_s[s2 * NHEAD + hh] + ad;
        float v3 = a_s[s3 * NHEAD + hh] + ad;
        float4 h0 = H4[(size_t)s0 * 24 + lane];
        float4 h1 = H4[(size_t)s1 * 24 + lane];
        float4 h2 = H4[(size_t)s2 * 24 + lane];
        float4 h3 = H4[(size_t)s3 * 24 + lane];
        v0 = v0 > 0.f ? v0 : 0.2f * v0;
        v1 = v1 > 0.f ? v1 : 0.2f * v1;
        v2 = v2 > 0.f ? v2 : 0.2f * v2;
        v3 = v3 > 0.f ? v3 : 0.2f * v3;
        float e0 = __expf(v0), e1 = __expf(v1), e2 = __expf(v2), e3 = __expf(v3);
        den += e0 + e1 + e2 + e3;
        acc.x = fmaf(e0, h0.x, acc.x); acc.y = fmaf(e0, h0.y, acc.y);
        acc.z = fmaf(e0, h0.z, acc.z); acc.w = fmaf(e0, h0.w, acc.w);
        acc.x = fmaf(e1, h1.x, acc.x); acc.y = fmaf(e1, h1.y, acc.y);
        acc.z = fmaf(e1, h1.z, acc.z); acc.w = fmaf(e1, h1.w, acc.w);
        acc.x = fmaf(e2, h2.x, acc.x); acc.y = fmaf(e2, h2.y, acc.y);
        acc.z = fmaf(e2, h2.z, acc.z); acc.w = fmaf(e2, h2.w, acc.w);
        acc.x = fmaf(e3, h3.x, acc.x); acc.y = fmaf(e3, h3.y, acc.y);
        acc.z = fmaf(e3, h3.z, acc.z); acc.w = fmaf(e3, h3.w, acc.w);
    }
    for (; j < j1; ++j) {
        int s = col[j];
        float v = a_s[s * NHEAD + hh] + ad;
        v = v > 0.f ? v : 0.2f * v;
        float ex = __expf(v);
        den += ex;
        float4 hv = H4[(size_t)s * 24 + lane];
        acc.x = fmaf(ex, hv.x, acc.x); acc.y = fmaf(ex, hv.y, acc.y);
        acc.z = fmaf(ex, hv.z, acc.z); acc.w = fmaf(ex, hv.w, acc.w);
    }
    float inv = 1.0f / den;
    float4 bv = ((const float4*)bias)[lane];
    float4 o;
    o.x = fmaf(acc.x, inv, bv.x); o.y = fmaf(acc.y, inv, bv.y);
    o.z = fmaf(acc.z, inv, bv.z); o.w = fmaf(acc.w, inv, bv.w);
    o.x = o.x > 0.f ? o.x : 0.f;  o.y = o.y > 0.f ? o.y : 0.f;
    o.z = o.z > 0.f ? o.z : 0.f;  o.w = o.w > 0.f ? o.w : 0.f;
    ((float4*)out)[(size_t)d * 24 + lane] = o;
}

extern "C" void kernel_launch(void* const* d_in, const int* in_sizes, int n_in,
                              void* d_out, int out_size, void* d_ws, size_t ws_size,
                              hipStream_t stream) {
    const float* x   = (const float*)d_in[0];
    const int*   ei  = (const int*)d_in[1];
    const float* W1  = (const float*)d_in[2];
    const float* as1 = (const float*)d_in[3];
    const float* ad1 = (const float*)d_in[4];
    const float* b1  = (const float*)d_in[5];
    const float* W2  = (const float*)d_in[6];
    const float* as2 = (const float*)d_in[7];
    const float* ad2 = (const float*)d_in[8];
    const float* b2  = (const float*)d_in[9];

    const int N    = in_sizes[0] / 128;   // 50000
    const int E0   = in_sizes[1] / 2;     // 800000
    const int Etot = E0 + N;
    const int* srci = ei;
    const int* dsti = ei + E0;
    const int nbkt = (N + 63) >> BSH;     // 782 buckets

    // -------- workspace layout --------
    char* wsb = (char*)d_ws;
    float* H   = (float*)wsb;                 wsb += (size_t)N * DMODEL * 4;
    float* H1  = (float*)wsb;                 wsb += (size_t)N * DMODEL * 4;
    float* AS  = (float*)wsb;                 wsb += (size_t)N * NHEAD * 4;
    float* AD  = (float*)wsb;                 wsb += (size_t)N * NHEAD * 4;
    int* DEG   = (int*)wsb;                   wsb += (size_t)N * 4;       // adjacent to BCNT:
    int* BCNT  = (int*)wsb;                   wsb += (size_t)nbkt * 4;    // single memset covers both
    int* ROWPTR= (int*)wsb;                   wsb += (size_t)(N + 1) * 4;
    int* CNT   = (int*)wsb;                   wsb += (size_t)N * 4;
    int* BSUM  = (int*)wsb;                   wsb += 256 * 4;
    int* COL   = (int*)wsb;                   wsb += (size_t)Etot * 4;
    wsb = (char*)(((uintptr_t)wsb + 15) & ~(uintptr_t)15);
    int2* BREC = (int2*)wsb;                  wsb += (size_t)nbkt * BCAP * 8;
    float* OUT = (float*)d_out;

    const int nb_scan   = (N + 1023) / 1024;
    const int gemm_grid = (N + 31) / 32;
    const int e2_grid   = (N + 15) / 16;
    const int edge_grid = (Etot + 255) / 256;

    // -------- CSR build (bucketed) --------
    hipMemsetAsync(DEG, 0, ((size_t)N + nbkt) * 4, stream);  // DEG + BCNT
    bucketA_kernel<<<edge_grid, 256, 0, stream>>>(srci, dsti, BCNT, DEG, BREC, E0, Etot);
    scan_block_kernel<<<nb_scan, 1024, 0, stream>>>(DEG, ROWPTR, BSUM, N);
    scan_bsum_kernel<<<1, 64, 0, stream>>>(BSUM, nb_scan);
    scan_add_kernel<<<(N + 255) / 256, 256, 0, stream>>>(ROWPTR, BSUM, N, Etot);
    hipMemcpyAsync(CNT, ROWPTR, (size_t)N * 4, hipMemcpyDeviceToDevice, stream);
    bucketB_kernel<<<nbkt, 256, 0, stream>>>(BCNT, BREC, CNT, COL);

    // -------- layer 1 --------
    gemm_att_fused<128><<<gemm_grid, 192, 0, stream>>>(x, W1, as1, ad1, H, AS, AD, N);
    edge2_vec_kernel<<<e2_grid, 384, 0, stream>>>(ROWPTR, COL, H, AS, AD, b1, H1, N);

    // -------- layer 2 --------
    gemm_att_fused<96><<<gemm_grid, 192, 0, stream>>>(H1, W2, as2, ad2, H, AS, AD, N);
    edge2_vec_kernel<<<e2_grid, 384, 0, stream>>>(ROWPTR, COL, H, AS, AD, b2, OUT, N);
}

// Round 6
// 256.602 us; speedup vs baseline: 1.9153x; 1.9153x over previous
//
#include <hip/hip_runtime.h>
#include <hip/hip_bf16.h>

#define NHEAD 8
#define CDIM 12
#define DMODEL 96
#define NBLK 128        // blocks in the counting-sort pass

// ---------------- fused GEMM + attention coefficients ----------------
template<int K>
__global__ __launch_bounds__(192) void gemm_att_fused(
    const float* __restrict__ X, const float* __restrict__ W,
    const float* __restrict__ att_s, const float* __restrict__ att_d,
    float* __restrict__ H, float* __restrict__ a_s, float* __restrict__ a_d,
    int N)
{
    constexpr int KQ = K / 4;
    __shared__ float xs[K][40];        // X^T tile, XOR-swizzled cols
    __shared__ float wsh[32 * 96];     // W chunk (32 rows, 12 KB)
    __shared__ float red[32][16];      // [node][head*2 + (s|d)]
    const int t  = threadIdx.x;
    const int c4 = t / 8;              // 0..23
    const int y  = t % 8;              // 0..7
    const int n0 = blockIdx.x * 32;

    for (int e = t; e < 512; e += 192) ((float*)red)[e] = 0.f;

    for (int e = t; e < 32 * KQ; e += 192) {
        int n = e / KQ, kq = e % KQ;
        int gn = n0 + n;
        float4 v = make_float4(0.f, 0.f, 0.f, 0.f);
        if (gn < N) v = ((const float4*)(X + (size_t)gn * K))[kq];
        int ncol = n ^ ((kq & 7) << 2);
        xs[4 * kq + 0][ncol] = v.x;
        xs[4 * kq + 1][ncol] = v.y;
        xs[4 * kq + 2][ncol] = v.z;
        xs[4 * kq + 3][ncol] = v.w;
    }

    float4 pref[4];
#pragma unroll
    for (int p = 0; p < 4; ++p)
        pref[p] = ((const float4*)W)[t + p * 192];

    float4 acc[4];
#pragma unroll
    for (int i = 0; i < 4; ++i) acc[i] = make_float4(0.f, 0.f, 0.f, 0.f);

    for (int k0 = 0; k0 < K; k0 += 32) {
        __syncthreads();
#pragma unroll
        for (int p = 0; p < 4; ++p) ((float4*)wsh)[t + p * 192] = pref[p];
        __syncthreads();
        if (k0 + 32 < K) {
#pragma unroll
            for (int p = 0; p < 4; ++p)
                pref[p] = ((const float4*)(W + (size_t)(k0 + 32) * 96))[t + p * 192];
        }
#pragma unroll 4
        for (int kk = 0; kk < 32; ++kk) {
            const int k = k0 + kk;
            const float4 wv = *(const float4*)&wsh[kk * 96 + c4 * 4];
            const int q = (k >> 2) & 7;
            const float4 xv = *(const float4*)&xs[k][4 * (y ^ q)];
            acc[0].x = fmaf(xv.x, wv.x, acc[0].x);
            acc[0].y = fmaf(xv.x, wv.y, acc[0].y);
            acc[0].z = fmaf(xv.x, wv.z, acc[0].z);
            acc[0].w = fmaf(xv.x, wv.w, acc[0].w);
            acc[1].x = fmaf(xv.y, wv.x, acc[1].x);
            acc[1].y = fmaf(xv.y, wv.y, acc[1].y);
            acc[1].z = fmaf(xv.y, wv.z, acc[1].z);
            acc[1].w = fmaf(xv.y, wv.w, acc[1].w);
            acc[2].x = fmaf(xv.z, wv.x, acc[2].x);
            acc[2].y = fmaf(xv.z, wv.y, acc[2].y);
            acc[2].z = fmaf(xv.z, wv.z, acc[2].z);
            acc[2].w = fmaf(xv.z, wv.w, acc[2].w);
            acc[3].x = fmaf(xv.w, wv.x, acc[3].x);
            acc[3].y = fmaf(xv.w, wv.y, acc[3].y);
            acc[3].z = fmaf(xv.w, wv.z, acc[3].z);
            acc[3].w = fmaf(xv.w, wv.w, acc[3].w);
        }
    }

    const int h = c4 / 3;
    const float4 asv = ((const float4*)att_s)[c4];
    const float4 adv = ((const float4*)att_d)[c4];
#pragma unroll
    for (int i = 0; i < 4; ++i) {
        const int m = 4 * y + i;
        float ps = acc[i].x * asv.x + acc[i].y * asv.y
                 + acc[i].z * asv.z + acc[i].w * asv.w;
        float pd = acc[i].x * adv.x + acc[i].y * adv.y
                 + acc[i].z * adv.z + acc[i].w * adv.w;
        atomicAdd(&red[m][h * 2 + 0], ps);
        atomicAdd(&red[m][h * 2 + 1], pd);
    }

#pragma unroll
    for (int i = 0; i < 4; ++i) {
        const int gn = n0 + 4 * y + i;
        if (gn < N) ((float4*)(H + (size_t)gn * 96))[c4] = acc[i];
    }

    __syncthreads();
    for (int e = t; e < 256; e += 192) {
        const int m = e >> 3, hh = e & 7;
        const int gn = n0 + m;
        if (gn < N) {
            a_s[gn * NHEAD + hh] = red[m][hh * 2 + 0];
            a_d[gn * NHEAD + hh] = red[m][hh * 2 + 1];
        }
    }
}

// ---------------- CSR build: two-level counting sort, no global atomics ----
// Pass 1: per-block LDS histogram over buckets (64 nodes each), stored
// bin-major hist2d[bin][blk].
__global__ __launch_bounds__(1024) void hist2d_kernel(
    const int* __restrict__ dsti, int* __restrict__ hist2d,
    int E0, int Etot, int nbins)
{
    __shared__ int hist[1024];
    const int t = threadIdx.x, b = blockIdx.x;
    hist[t] = 0;
    __syncthreads();
    const int chunk = (Etot + NBLK - 1) / NBLK;
    const int e0 = b * chunk;
    const int e1 = (e0 + chunk < Etot) ? e0 + chunk : Etot;
    for (int e = e0 + t; e < e1; e += 1024) {
        int d = (e < E0) ? dsti[e] : e - E0;
        atomicAdd(&hist[d >> 6], 1);
    }
    __syncthreads();
    if (t < nbins) hist2d[(size_t)t * NBLK + b] = hist[t];
}

// Pass 2: re-read edges, rank via LDS counters, write (d,s) records into the
// (block,bin) segment given by the scanned histogram. Contiguous-per-segment.
__global__ __launch_bounds__(1024) void place_kernel(
    const int* __restrict__ srci, const int* __restrict__ dsti,
    const int* __restrict__ sc2d, int2* __restrict__ rec,
    int E0, int Etot)
{
    __shared__ int run[1024];
    const int t = threadIdx.x, b = blockIdx.x;
    run[t] = 0;
    __syncthreads();
    const int chunk = (Etot + NBLK - 1) / NBLK;
    const int e0 = b * chunk;
    const int e1 = (e0 + chunk < Etot) ? e0 + chunk : Etot;
    for (int e = e0 + t; e < e1; e += 1024) {
        int s, d;
        if (e < E0) { s = srci[e]; d = dsti[e]; }
        else        { s = d = e - E0; }
        int bin = d >> 6;
        int r = atomicAdd(&run[bin], 1);
        rec[(size_t)sc2d[bin * NBLK + b] + r] = make_int2(d, s);
    }
}

// Per-bucket degree counts (LDS only, no global atomics).
__global__ __launch_bounds__(256) void bucketDeg_kernel(
    const int* __restrict__ sc2d, const int2* __restrict__ rec,
    int* __restrict__ deg, int N)
{
    __shared__ int deg64[64];
    const int t = threadIdx.x, b = blockIdx.x;
    if (t < 64) deg64[t] = 0;
    __syncthreads();
    const int r0 = sc2d[b * NBLK], r1 = sc2d[(b + 1) * NBLK];
    for (int i = r0 + t; i < r1; i += 256)
        atomicAdd(&deg64[rec[i].x & 63], 1);
    __syncthreads();
    const int gn = b * 64 + t;
    if (t < 64 && gn < N) deg[gn] = deg64[t];
}

// Per-bucket scatter into final CSR col[] (contiguous ~4KB window per bucket).
__global__ __launch_bounds__(256) void bucketC_kernel(
    const int* __restrict__ sc2d, const int2* __restrict__ rec,
    const int* __restrict__ rowptr, int* __restrict__ col)
{
    __shared__ int run64[64];
    const int t = threadIdx.x, b = blockIdx.x;
    if (t < 64) run64[t] = 0;
    __syncthreads();
    const int r0 = sc2d[b * NBLK], r1 = sc2d[(b + 1) * NBLK];
    for (int i = r0 + t; i < r1; i += 256) {
        int2 v = rec[i];
        int rank = atomicAdd(&run64[v.x & 63], 1);
        col[rowptr[v.x] + rank] = v.y;
    }
}

// ---------------- generic scan chain (exclusive) ----------------
__global__ __launch_bounds__(1024) void scan_block_kernel(
    const int* __restrict__ in, int* __restrict__ out,
    int* __restrict__ bsum, int n)
{
    __shared__ int sh[1024];
    int t = threadIdx.x, g = blockIdx.x * 1024 + t;
    int v = (g < n) ? in[g] : 0;
    sh[t] = v;
    __syncthreads();
    for (int off = 1; off < 1024; off <<= 1) {
        int add = (t >= off) ? sh[t - off] : 0;
        __syncthreads();
        sh[t] += add;
        __syncthreads();
    }
    if (g < n) out[g] = sh[t] - v;     // exclusive
    if (t == 1023) bsum[blockIdx.x] = sh[t];
}

__global__ void scan_bsum_kernel(int* bsum, int nb)
{
    if (threadIdx.x == 0) {
        int acc = 0;
        for (int i = 0; i < nb; ++i) { int v = bsum[i]; bsum[i] = acc; acc += v; }
    }
}

__global__ void scan_add_kernel(int* __restrict__ arr, const int* __restrict__ bsum,
                                int n, int total)
{
    int g = blockIdx.x * blockDim.x + threadIdx.x;
    if (g < n) arr[g] += bsum[g >> 10];
    if (g == 0) arr[n] = total;        // sentinel
}

// ---------------- edge pass (CSR): gather + fused softmax-denominator ------
__global__ __launch_bounds__(384) void edge2_vec_kernel(
    const int* __restrict__ rowptr, const int* __restrict__ col,
    const float* __restrict__ H, const float* __restrict__ a_s,
    const float* __restrict__ a_d, const float* __restrict__ bias,
    float* __restrict__ out, int N)
{
    const int grp  = threadIdx.x / 24;      // 16 nodes/block
    const int lane = threadIdx.x % 24;      // float4 chunk
    const int d = blockIdx.x * 16 + grp;
    if (d >= N) return;
    const int hh = lane / 3;
    const float ad  = a_d[d * NHEAD + hh];
    const float4* __restrict__ H4 = (const float4*)H;

    int j0 = rowptr[d], j1 = rowptr[d + 1];
    float4 acc = make_float4(0.f, 0.f, 0.f, 0.f);
    float den = 1e-16f;
    int j = j0;
    for (; j + 3 < j1; j += 4) {
        int s0 = col[j], s1 = col[j+1], s2 = col[j+2], s3 = col[j+3];
        float v0 = a_s[s0 * NHEAD + hh] + ad;
        float v1 = a_s[s1 * NHEAD + hh] + ad;
        float v2 = a_s[s2 * NHEAD + hh] + ad;
        float v3 = a_s[s3 * NHEAD + hh] + ad;
        float4 h0 = H4[(size_t)s0 * 24 + lane];
        float4 h1 = H4[(size_t)s1 * 24 + lane];
        float4 h2 = H4[(size_t)s2 * 24 + lane];
        float4 h3 = H4[(size_t)s3 * 24 + lane];
        v0 = v0 > 0.f ? v0 : 0.2f * v0;
        v1 = v1 > 0.f ? v1 : 0.2f * v1;
        v2 = v2 > 0.f ? v2 : 0.2f * v2;
        v3 = v3 > 0.f ? v3 : 0.2f * v3;
        float e0 = __expf(v0), e1 = __expf(v1), e2 = __expf(v2), e3 = __expf(v3);
        den += e0 + e1 + e2 + e3;
        acc.x = fmaf(e0, h0.x, acc.x); acc.y = fmaf(e0, h0.y, acc.y);
        acc.z = fmaf(e0, h0.z, acc.z); acc.w = fmaf(e0, h0.w, acc.w);
        acc.x = fmaf(e1, h1.x, acc.x); acc.y = fmaf(e1, h1.y, acc.y);
        acc.z = fmaf(e1, h1.z, acc.z); acc.w = fmaf(e1, h1.w, acc.w);
        acc.x = fmaf(e2, h2.x, acc.x); acc.y = fmaf(e2, h2.y, acc.y);
        acc.z = fmaf(e2, h2.z, acc.z); acc.w = fmaf(e2, h2.w, acc.w);
        acc.x = fmaf(e3, h3.x, acc.x); acc.y = fmaf(e3, h3.y, acc.y);
        acc.z = fmaf(e3, h3.z, acc.z); acc.w = fmaf(e3, h3.w, acc.w);
    }
    for (; j < j1; ++j) {
        int s = col[j];
        float v = a_s[s * NHEAD + hh] + ad;
        v = v > 0.f ? v : 0.2f * v;
        float ex = __expf(v);
        den += ex;
        float4 hv = H4[(size_t)s * 24 + lane];
        acc.x = fmaf(ex, hv.x, acc.x); acc.y = fmaf(ex, hv.y, acc.y);
        acc.z = fmaf(ex, hv.z, acc.z); acc.w = fmaf(ex, hv.w, acc.w);
    }
    float inv = 1.0f / den;
    float4 bv = ((const float4*)bias)[lane];
    float4 o;
    o.x = fmaf(acc.x, inv, bv.x); o.y = fmaf(acc.y, inv, bv.y);
    o.z = fmaf(acc.z, inv, bv.z); o.w = fmaf(acc.w, inv, bv.w);
    o.x = o.x > 0.f ? o.x : 0.f;  o.y = o.y > 0.f ? o.y : 0.f;
    o.z = o.z > 0.f ? o.z : 0.f;  o.w = o.w > 0.f ? o.w : 0.f;
    ((float4*)out)[(size_t)d * 24 + lane] = o;
}

extern "C" void kernel_launch(void* const* d_in, const int* in_sizes, int n_in,
                              void* d_out, int out_size, void* d_ws, size_t ws_size,
                              hipStream_t stream) {
    const float* x   = (const float*)d_in[0];
    const int*   ei  = (const int*)d_in[1];
    const float* W1  = (const float*)d_in[2];
    const float* as1 = (const float*)d_in[3];
    const float* ad1 = (const float*)d_in[4];
    const float* b1  = (const float*)d_in[5];
    const float* W2  = (const float*)d_in[6];
    const float* as2 = (const float*)d_in[7];
    const float* ad2 = (const float*)d_in[8];
    const float* b2  = (const float*)d_in[9];

    const int N    = in_sizes[0] / 128;   // 50000
    const int E0   = in_sizes[1] / 2;     // 800000
    const int Etot = E0 + N;
    const int* srci = ei;
    const int* dsti = ei + E0;
    const int nbins = (N + 63) >> 6;      // 782
    const int M2    = nbins * NBLK;       // 100096

    // -------- workspace layout --------
    char* wsb = (char*)d_ws;
    float* H    = (float*)wsb;            wsb += (size_t)N * DMODEL * 4;
    float* H1   = (float*)wsb;            wsb += (size_t)N * DMODEL * 4;
    float* AS   = (float*)wsb;            wsb += (size_t)N * NHEAD * 4;
    float* AD   = (float*)wsb;            wsb += (size_t)N * NHEAD * 4;
    int* HIST2D = (int*)wsb;              wsb += (size_t)M2 * 4;
    int* SC2D   = (int*)wsb;              wsb += (size_t)(M2 + 1) * 4;
    int* DEG    = (int*)wsb;              wsb += (size_t)N * 4;
    int* ROWPTR = (int*)wsb;              wsb += (size_t)(N + 1) * 4;
    int* BSUM   = (int*)wsb;              wsb += 256 * 4;
    int* COL    = (int*)wsb;              wsb += (size_t)Etot * 4;
    wsb = (char*)(((uintptr_t)wsb + 15) & ~(uintptr_t)15);
    int2* REC   = (int2*)wsb;             wsb += (size_t)Etot * 8;
    float* OUT  = (float*)d_out;

    const int nb2       = (M2 + 1023) / 1024;   // 98
    const int nb_scan   = (N + 1023) / 1024;    // 49
    const int gemm_grid = (N + 31) / 32;
    const int e2_grid   = (N + 15) / 16;

    // -------- CSR build: counting sort, zero global atomics --------
    hist2d_kernel<<<NBLK, 1024, 0, stream>>>(dsti, HIST2D, E0, Etot, nbins);
    scan_block_kernel<<<nb2, 1024, 0, stream>>>(HIST2D, SC2D, BSUM, M2);
    scan_bsum_kernel<<<1, 64, 0, stream>>>(BSUM, nb2);
    scan_add_kernel<<<(M2 + 255) / 256, 256, 0, stream>>>(SC2D, BSUM, M2, Etot);
    place_kernel<<<NBLK, 1024, 0, stream>>>(srci, dsti, SC2D, REC, E0, Etot);
    bucketDeg_kernel<<<nbins, 256, 0, stream>>>(SC2D, REC, DEG, N);
    scan_block_kernel<<<nb_scan, 1024, 0, stream>>>(DEG, ROWPTR, BSUM, N);
    scan_bsum_kernel<<<1, 64, 0, stream>>>(BSUM, nb_scan);
    scan_add_kernel<<<(N + 255) / 256, 256, 0, stream>>>(ROWPTR, BSUM, N, Etot);
    bucketC_kernel<<<nbins, 256, 0, stream>>>(SC2D, REC, ROWPTR, COL);

    // -------- layer 1 --------
    gemm_att_fused<128><<<gemm_grid, 192, 0, stream>>>(x, W1, as1, ad1, H, AS, AD, N);
    edge2_vec_kernel<<<e2_grid, 384, 0, stream>>>(ROWPTR, COL, H, AS, AD, b1, H1, N);

    // -------- layer 2 --------
    gemm_att_fused<96><<<gemm_grid, 192, 0, stream>>>(H1, W2, as2, ad2, H, AS, AD, N);
    edge2_vec_kernel<<<e2_grid, 384, 0, stream>>>(ROWPTR, COL, H, AS, AD, b2, OUT, N);
}

// Round 7
// 253.779 us; speedup vs baseline: 1.9366x; 1.0111x over previous
//
#include <hip/hip_runtime.h>
#include <hip/hip_bf16.h>

#define NHEAD 8
#define CDIM 12
#define DMODEL 96
#define NBLK 128        // blocks in the counting-sort pass

// ---------------- fused GEMM + attention coefficients (v3: full pipeline) ---
// H[N,96] = X[N,K] @ W[K,96]; a_s/a_d fused. 192 threads = (c4=t/8, y=t%8),
// 32 nodes/block, 4x4 register tile/thread. Both X and W stream through
// 32-k-row LDS chunks with register double-buffering; LDS = 18.4 KB.
template<int K>
__global__ __launch_bounds__(192) void gemm_att_fused(
    const float* __restrict__ X, const float* __restrict__ W,
    const float* __restrict__ att_s, const float* __restrict__ att_d,
    float* __restrict__ H, float* __restrict__ a_s, float* __restrict__ a_d,
    int N)
{
    constexpr int KQ = K / 4;          // float4 per X row
    constexpr int NC = K / 32;         // k-chunks
    __shared__ float xs[32][32];       // X^T chunk, XOR-swizzled cols
    __shared__ float wsh[32 * 96];     // W chunk (12 KB)
    __shared__ float red[32][16];      // [node][head*2 + (s|d)]
    const int t  = threadIdx.x;
    const int c4 = t / 8;              // 0..23
    const int y  = t % 8;              // 0..7
    const int n0 = blockIdx.x * 32;
    const float4 z4 = make_float4(0.f, 0.f, 0.f, 0.f);

    for (int e = t; e < 512; e += 192) ((float*)red)[e] = 0.f;

    // X-chunk register prefetch: 256 float4 (32 nodes x 8 kq) over 192 threads
    const int xn0 = t >> 3,  xkq0 = t & 7;          // slot t
    const int xn1 = (t + 192) >> 3, xkq1 = (t + 192) & 7;  // slot t+192 (t<64)
    const int gn0 = n0 + xn0, gn1 = n0 + xn1;

    float4 px0, px1, pw[4];
    // ---- prefetch chunk 0 ----
    px0 = (gn0 < N) ? ((const float4*)X)[(size_t)gn0 * KQ + xkq0] : z4;
    if (t < 64) px1 = (gn1 < N) ? ((const float4*)X)[(size_t)gn1 * KQ + xkq1] : z4;
#pragma unroll
    for (int p = 0; p < 4; ++p) pw[p] = ((const float4*)W)[t + p * 192];

    float4 acc[4];
#pragma unroll
    for (int i = 0; i < 4; ++i) acc[i] = z4;

    for (int c = 0; c < NC; ++c) {
        __syncthreads();               // previous chunk fully consumed
        // ---- write prefetched chunk to LDS ----
        {
            const int col0 = xn0 ^ (xkq0 << 2);
            xs[4 * xkq0 + 0][col0] = px0.x;
            xs[4 * xkq0 + 1][col0] = px0.y;
            xs[4 * xkq0 + 2][col0] = px0.z;
            xs[4 * xkq0 + 3][col0] = px0.w;
            if (t < 64) {
                const int col1 = xn1 ^ (xkq1 << 2);
                xs[4 * xkq1 + 0][col1] = px1.x;
                xs[4 * xkq1 + 1][col1] = px1.y;
                xs[4 * xkq1 + 2][col1] = px1.z;
                xs[4 * xkq1 + 3][col1] = px1.w;
            }
#pragma unroll
            for (int p = 0; p < 4; ++p) ((float4*)wsh)[t + p * 192] = pw[p];
        }
        __syncthreads();
        // ---- issue next chunk's global loads (retire under FMAs) ----
        if (c + 1 < NC) {
            const int k0q = (c + 1) * 8;           // float4 offset in X row
            px0 = (gn0 < N) ? ((const float4*)X)[(size_t)gn0 * KQ + k0q + xkq0] : z4;
            if (t < 64)
                px1 = (gn1 < N) ? ((const float4*)X)[(size_t)gn1 * KQ + k0q + xkq1] : z4;
#pragma unroll
            for (int p = 0; p < 4; ++p)
                pw[p] = ((const float4*)W)[(c + 1) * 768 + t + p * 192];
        }
        // ---- compute 32 k-steps ----
#pragma unroll 4
        for (int kk = 0; kk < 32; ++kk) {
            const float4 wv = *(const float4*)&wsh[kk * 96 + c4 * 4];
            const int q = (kk >> 2) & 7;
            const float4 xv = *(const float4*)&xs[kk][4 * (y ^ q)];
            acc[0].x = fmaf(xv.x, wv.x, acc[0].x);
            acc[0].y = fmaf(xv.x, wv.y, acc[0].y);
            acc[0].z = fmaf(xv.x, wv.z, acc[0].z);
            acc[0].w = fmaf(xv.x, wv.w, acc[0].w);
            acc[1].x = fmaf(xv.y, wv.x, acc[1].x);
            acc[1].y = fmaf(xv.y, wv.y, acc[1].y);
            acc[1].z = fmaf(xv.y, wv.z, acc[1].z);
            acc[1].w = fmaf(xv.y, wv.w, acc[1].w);
            acc[2].x = fmaf(xv.z, wv.x, acc[2].x);
            acc[2].y = fmaf(xv.z, wv.y, acc[2].y);
            acc[2].z = fmaf(xv.z, wv.z, acc[2].z);
            acc[2].w = fmaf(xv.z, wv.w, acc[2].w);
            acc[3].x = fmaf(xv.w, wv.x, acc[3].x);
            acc[3].y = fmaf(xv.w, wv.y, acc[3].y);
            acc[3].z = fmaf(xv.w, wv.z, acc[3].z);
            acc[3].w = fmaf(xv.w, wv.w, acc[3].w);
        }
    }

    const int h = c4 / 3;
    const float4 asv = ((const float4*)att_s)[c4];
    const float4 adv = ((const float4*)att_d)[c4];
#pragma unroll
    for (int i = 0; i < 4; ++i) {
        const int m = 4 * y + i;
        float ps = acc[i].x * asv.x + acc[i].y * asv.y
                 + acc[i].z * asv.z + acc[i].w * asv.w;
        float pd = acc[i].x * adv.x + acc[i].y * adv.y
                 + acc[i].z * adv.z + acc[i].w * adv.w;
        atomicAdd(&red[m][h * 2 + 0], ps);
        atomicAdd(&red[m][h * 2 + 1], pd);
    }

#pragma unroll
    for (int i = 0; i < 4; ++i) {
        const int gn = n0 + 4 * y + i;
        if (gn < N) ((float4*)(H + (size_t)gn * 96))[c4] = acc[i];
    }

    __syncthreads();
    for (int e = t; e < 256; e += 192) {
        const int m = e >> 3, hh = e & 7;
        const int gn = n0 + m;
        if (gn < N) {
            a_s[gn * NHEAD + hh] = red[m][hh * 2 + 0];
            a_d[gn * NHEAD + hh] = red[m][hh * 2 + 1];
        }
    }
}

// ---------------- CSR build: two-level counting sort, no global atomics ----
__global__ __launch_bounds__(1024) void hist2d_kernel(
    const int* __restrict__ dsti, int* __restrict__ hist2d,
    int E0, int Etot, int nbins)
{
    __shared__ int hist[1024];
    const int t = threadIdx.x, b = blockIdx.x;
    hist[t] = 0;
    __syncthreads();
    const int chunk = (Etot + NBLK - 1) / NBLK;
    const int e0 = b * chunk;
    const int e1 = (e0 + chunk < Etot) ? e0 + chunk : Etot;
    for (int e = e0 + t; e < e1; e += 1024) {
        int d = (e < E0) ? dsti[e] : e - E0;
        atomicAdd(&hist[d >> 6], 1);
    }
    __syncthreads();
    if (t < nbins) hist2d[(size_t)t * NBLK + b] = hist[t];
}

__global__ __launch_bounds__(1024) void place_kernel(
    const int* __restrict__ srci, const int* __restrict__ dsti,
    const int* __restrict__ sc2d, int2* __restrict__ rec,
    int E0, int Etot)
{
    __shared__ int run[1024];
    const int t = threadIdx.x, b = blockIdx.x;
    run[t] = 0;
    __syncthreads();
    const int chunk = (Etot + NBLK - 1) / NBLK;
    const int e0 = b * chunk;
    const int e1 = (e0 + chunk < Etot) ? e0 + chunk : Etot;
    for (int e = e0 + t; e < e1; e += 1024) {
        int s, d;
        if (e < E0) { s = srci[e]; d = dsti[e]; }
        else        { s = d = e - E0; }
        int bin = d >> 6;
        int r = atomicAdd(&run[bin], 1);
        rec[(size_t)sc2d[bin * NBLK + b] + r] = make_int2(d, s);
    }
}

__global__ __launch_bounds__(256) void bucketDeg_kernel(
    const int* __restrict__ sc2d, const int2* __restrict__ rec,
    int* __restrict__ deg, int N)
{
    __shared__ int deg64[64];
    const int t = threadIdx.x, b = blockIdx.x;
    if (t < 64) deg64[t] = 0;
    __syncthreads();
    const int r0 = sc2d[b * NBLK], r1 = sc2d[(b + 1) * NBLK];
    for (int i = r0 + t; i < r1; i += 256)
        atomicAdd(&deg64[rec[i].x & 63], 1);
    __syncthreads();
    const int gn = b * 64 + t;
    if (t < 64 && gn < N) deg[gn] = deg64[t];
}

__global__ __launch_bounds__(256) void bucketC_kernel(
    const int* __restrict__ sc2d, const int2* __restrict__ rec,
    const int* __restrict__ rowptr, int* __restrict__ col)
{
    __shared__ int run64[64];
    const int t = threadIdx.x, b = blockIdx.x;
    if (t < 64) run64[t] = 0;
    __syncthreads();
    const int r0 = sc2d[b * NBLK], r1 = sc2d[(b + 1) * NBLK];
    for (int i = r0 + t; i < r1; i += 256) {
        int2 v = rec[i];
        int rank = atomicAdd(&run64[v.x & 63], 1);
        col[rowptr[v.x] + rank] = v.y;
    }
}

// ---------------- generic scan chain (exclusive) ----------------
__global__ __launch_bounds__(1024) void scan_block_kernel(
    const int* __restrict__ in, int* __restrict__ out,
    int* __restrict__ bsum, int n)
{
    __shared__ int sh[1024];
    int t = threadIdx.x, g = blockIdx.x * 1024 + t;
    int v = (g < n) ? in[g] : 0;
    sh[t] = v;
    __syncthreads();
    for (int off = 1; off < 1024; off <<= 1) {
        int add = (t >= off) ? sh[t - off] : 0;
        __syncthreads();
        sh[t] += add;
        __syncthreads();
    }
    if (g < n) out[g] = sh[t] - v;     // exclusive
    if (t == 1023) bsum[blockIdx.x] = sh[t];
}

__global__ void scan_bsum_kernel(int* bsum, int nb)
{
    if (threadIdx.x == 0) {
        int acc = 0;
        for (int i = 0; i < nb; ++i) { int v = bsum[i]; bsum[i] = acc; acc += v; }
    }
}

__global__ void scan_add_kernel(int* __restrict__ arr, const int* __restrict__ bsum,
                                int n, int total)
{
    int g = blockIdx.x * blockDim.x + threadIdx.x;
    if (g < n) arr[g] += bsum[g >> 10];
    if (g == 0) arr[n] = total;        // sentinel
}

// ---------------- edge pass (CSR): gather + fused softmax-denominator ------
__global__ __launch_bounds__(384) void edge2_vec_kernel(
    const int* __restrict__ rowptr, const int* __restrict__ col,
    const float* __restrict__ H, const float* __restrict__ a_s,
    const float* __restrict__ a_d, const float* __restrict__ bias,
    float* __restrict__ out, int N)
{
    const int grp  = threadIdx.x / 24;      // 16 nodes/block
    const int lane = threadIdx.x % 24;      // float4 chunk
    const int d = blockIdx.x * 16 + grp;
    if (d >= N) return;
    const int hh = lane / 3;
    const float ad  = a_d[d * NHEAD + hh];
    const float4* __restrict__ H4 = (const float4*)H;

    int j0 = rowptr[d], j1 = rowptr[d + 1];
    float4 acc = make_float4(0.f, 0.f, 0.f, 0.f);
    float den = 1e-16f;
    int j = j0;
    for (; j + 3 < j1; j += 4) {
        int s0 = col[j], s1 = col[j+1], s2 = col[j+2], s3 = col[j+3];
        float v0 = a_s[s0 * NHEAD + hh] + ad;
        float v1 = a_s[s1 * NHEAD + hh] + ad;
        float v2 = a_s[s2 * NHEAD + hh] + ad;
        float v3 = a_s[s3 * NHEAD + hh] + ad;
        float4 h0 = H4[(size_t)s0 * 24 + lane];
        float4 h1 = H4[(size_t)s1 * 24 + lane];
        float4 h2 = H4[(size_t)s2 * 24 + lane];
        float4 h3 = H4[(size_t)s3 * 24 + lane];
        v0 = v0 > 0.f ? v0 : 0.2f * v0;
        v1 = v1 > 0.f ? v1 : 0.2f * v1;
        v2 = v2 > 0.f ? v2 : 0.2f * v2;
        v3 = v3 > 0.f ? v3 : 0.2f * v3;
        float e0 = __expf(v0), e1 = __expf(v1), e2 = __expf(v2), e3 = __expf(v3);
        den += e0 + e1 + e2 + e3;
        acc.x = fmaf(e0, h0.x, acc.x); acc.y = fmaf(e0, h0.y, acc.y);
        acc.z = fmaf(e0, h0.z, acc.z); acc.w = fmaf(e0, h0.w, acc.w);
        acc.x = fmaf(e1, h1.x, acc.x); acc.y = fmaf(e1, h1.y, acc.y);
        acc.z = fmaf(e1, h1.z, acc.z); acc.w = fmaf(e1, h1.w, acc.w);
        acc.x = fmaf(e2, h2.x, acc.x); acc.y = fmaf(e2, h2.y, acc.y);
        acc.z = fmaf(e2, h2.z, acc.z); acc.w = fmaf(e2, h2.w, acc.w);
        acc.x = fmaf(e3, h3.x, acc.x); acc.y = fmaf(e3, h3.y, acc.y);
        acc.z = fmaf(e3, h3.z, acc.z); acc.w = fmaf(e3, h3.w, acc.w);
    }
    for (; j < j1; ++j) {
        int s = col[j];
        float v = a_s[s * NHEAD + hh] + ad;
        v = v > 0.f ? v : 0.2f * v;
        float ex = __expf(v);
        den += ex;
        float4 hv = H4[(size_t)s * 24 + lane];
        acc.x = fmaf(ex, hv.x, acc.x); acc.y = fmaf(ex, hv.y, acc.y);
        acc.z = fmaf(ex, hv.z, acc.z); acc.w = fmaf(ex, hv.w, acc.w);
    }
    float inv = 1.0f / den;
    float4 bv = ((const float4*)bias)[lane];
    float4 o;
    o.x = fmaf(acc.x, inv, bv.x); o.y = fmaf(acc.y, inv, bv.y);
    o.z = fmaf(acc.z, inv, bv.z); o.w = fmaf(acc.w, inv, bv.w);
    o.x = o.x > 0.f ? o.x : 0.f;  o.y = o.y > 0.f ? o.y : 0.f;
    o.z = o.z > 0.f ? o.z : 0.f;  o.w = o.w > 0.f ? o.w : 0.f;
    ((float4*)out)[(size_t)d * 24 + lane] = o;
}

extern "C" void kernel_launch(void* const* d_in, const int* in_sizes, int n_in,
                              void* d_out, int out_size, void* d_ws, size_t ws_size,
                              hipStream_t stream) {
    const float* x   = (const float*)d_in[0];
    const int*   ei  = (const int*)d_in[1];
    const float* W1  = (const float*)d_in[2];
    const float* as1 = (const float*)d_in[3];
    const float* ad1 = (const float*)d_in[4];
    const float* b1  = (const float*)d_in[5];
    const float* W2  = (const float*)d_in[6];
    const float* as2 = (const float*)d_in[7];
    const float* ad2 = (const float*)d_in[8];
    const float* b2  = (const float*)d_in[9];

    const int N    = in_sizes[0] / 128;   // 50000
    const int E0   = in_sizes[1] / 2;     // 800000
    const int Etot = E0 + N;
    const int* srci = ei;
    const int* dsti = ei + E0;
    const int nbins = (N + 63) >> 6;      // 782
    const int M2    = nbins * NBLK;       // 100096

    // -------- workspace layout --------
    char* wsb = (char*)d_ws;
    float* H    = (float*)wsb;            wsb += (size_t)N * DMODEL * 4;
    float* H1   = (float*)wsb;            wsb += (size_t)N * DMODEL * 4;
    float* AS   = (float*)wsb;            wsb += (size_t)N * NHEAD * 4;
    float* AD   = (float*)wsb;            wsb += (size_t)N * NHEAD * 4;
    int* HIST2D = (int*)wsb;              wsb += (size_t)M2 * 4;
    int* SC2D   = (int*)wsb;              wsb += (size_t)(M2 + 1) * 4;
    int* DEG    = (int*)wsb;              wsb += (size_t)N * 4;
    int* ROWPTR = (int*)wsb;              wsb += (size_t)(N + 1) * 4;
    int* BSUM   = (int*)wsb;              wsb += 256 * 4;
    int* COL    = (int*)wsb;              wsb += (size_t)Etot * 4;
    wsb = (char*)(((uintptr_t)wsb + 15) & ~(uintptr_t)15);
    int2* REC   = (int2*)wsb;             wsb += (size_t)Etot * 8;
    float* OUT  = (float*)d_out;

    const int nb2       = (M2 + 1023) / 1024;   // 98
    const int nb_scan   = (N + 1023) / 1024;    // 49
    const int gemm_grid = (N + 31) / 32;
    const int e2_grid   = (N + 15) / 16;

    // -------- CSR build: counting sort, zero global atomics --------
    hist2d_kernel<<<NBLK, 1024, 0, stream>>>(dsti, HIST2D, E0, Etot, nbins);
    scan_block_kernel<<<nb2, 1024, 0, stream>>>(HIST2D, SC2D, BSUM, M2);
    scan_bsum_kernel<<<1, 64, 0, stream>>>(BSUM, nb2);
    scan_add_kernel<<<(M2 + 255) / 256, 256, 0, stream>>>(SC2D, BSUM, M2, Etot);
    place_kernel<<<NBLK, 1024, 0, stream>>>(srci, dsti, SC2D, REC, E0, Etot);
    bucketDeg_kernel<<<nbins, 256, 0, stream>>>(SC2D, REC, DEG, N);
    scan_block_kernel<<<nb_scan, 1024, 0, stream>>>(DEG, ROWPTR, BSUM, N);
    scan_bsum_kernel<<<1, 64, 0, stream>>>(BSUM, nb_scan);
    scan_add_kernel<<<(N + 255) / 256, 256, 0, stream>>>(ROWPTR, BSUM, N, Etot);
    bucketC_kernel<<<nbins, 256, 0, stream>>>(SC2D, REC, ROWPTR, COL);

    // -------- layer 1 --------
    gemm_att_fused<128><<<gemm_grid, 192, 0, stream>>>(x, W1, as1, ad1, H, AS, AD, N);
    edge2_vec_kernel<<<e2_grid, 384, 0, stream>>>(ROWPTR, COL, H, AS, AD, b1, H1, N);

    // -------- layer 2 --------
    gemm_att_fused<96><<<gemm_grid, 192, 0, stream>>>(H1, W2, as2, ad2, H, AS, AD, N);
    edge2_vec_kernel<<<e2_grid, 384, 0, stream>>>(ROWPTR, COL, H, AS, AD, b2, OUT, N);
}